// Round 7
// baseline (379.660 us; speedup 1.0000x reference)
//
#include <hip/hip_runtime.h>
#include <stdint.h>

typedef unsigned short u16;
typedef __attribute__((ext_vector_type(8))) short bf16x8;
typedef __attribute__((ext_vector_type(4))) float f32x4;

#define S_LEN 1024
#define BATCH 4
#define EMB   1024
#define NH    16
#define DHEAD 64
#define BHEAD 64
#define NTOK  4096
#define KDIM  1024
#define NDIM  1024
#define EPSF  1e-8f
#define LOG2E 1.4426950408889634f

#define MFMA16(a,b,c) __builtin_amdgcn_mfma_f32_16x16x32_bf16((a),(b),(c),0,0,0)

#define GLOAD16(g, l) __builtin_amdgcn_global_load_lds( \
    (const __attribute__((address_space(1))) void*)(g), \
    (__attribute__((address_space(3))) void*)(l), 16, 0, 0)

#define EXP2F(x) __builtin_amdgcn_exp2f(x)

// values at all call sites are exact small integers (|v| <= 255): bf16 = top 16 bits
__device__ __forceinline__ u16 f2bf(float f){
  return (u16)(__float_as_uint(f) >> 16);
}

__device__ __forceinline__ float wave_max(float v){
#pragma unroll
  for (int off = 32; off > 0; off >>= 1) v = fmaxf(v, __shfl_xor(v, off));
  return v;
}

// ---------------- scale slots ----------------
// 0 amax_query 1 amax_key 2 amax_value 3 amax_Wq 4 amax_Wk 5 amax_Wv 6 amax_Wo
// 7 amax_qproj 8 amax_kproj 9 amax_vproj 10 amax_attnout 11 s_a 12 dummy 13 inv_l_max

__global__ void k_zero(float* sc){
  if (threadIdx.x < 16) sc[threadIdx.x] = 0.0f;
}

struct AQDesc { const float* x; u16* y; int n4; int slot; float qdiv; float lo; };
struct AQTable { AQDesc d[7]; };

// merged absmax over 7 tensors; grid = 2048 (3x512 for q/k/v, 4x128 for weights)
__global__ __launch_bounds__(256) void k_absmax7(AQTable t, int* __restrict__ sci){
  const int bid = blockIdx.x;
  int seg, b0, nb;
  if (bid < 1536){ seg = bid >> 9; b0 = seg << 9; nb = 512; }
  else { seg = 3 + ((bid - 1536) >> 7); b0 = 1536 + ((seg - 3) << 7); nb = 128; }
  const AQDesc D = t.d[seg];
  float m = 0.0f;
  const float4* x4 = (const float4*)D.x;
  for (int i = (bid - b0)*256 + threadIdx.x; i < D.n4; i += nb*256){
    float4 v = x4[i];
    m = fmaxf(m, fmaxf(fmaxf(fabsf(v.x), fabsf(v.y)), fmaxf(fabsf(v.z), fabsf(v.w))));
  }
  m = wave_max(m);
  __shared__ float red[4];
  int lane = threadIdx.x & 63, w = threadIdx.x >> 6;
  if (lane == 0) red[w] = m;
  __syncthreads();
  if (threadIdx.x == 0){
    float mm = fmaxf(fmaxf(red[0], red[1]), fmaxf(red[2], red[3]));
    atomicMax(sci + D.slot, __float_as_int(mm));
  }
}

// merged fake-quant of 7 tensors to integer grid stored as bf16 ints
__global__ __launch_bounds__(256) void k_quant7(AQTable t, const float* __restrict__ sc){
  const int bid = blockIdx.x;
  int seg, b0, nb;
  if (bid < 1536){ seg = bid >> 9; b0 = seg << 9; nb = 512; }
  else { seg = 3 + ((bid - 1536) >> 7); b0 = 1536 + ((seg - 3) << 7); nb = 128; }
  const AQDesc D = t.d[seg];
  const float s = fmaxf(sc[D.slot] / D.qdiv, EPSF);
  const float lo = D.lo;
  const float4* x4 = (const float4*)D.x;
  for (int i = (bid - b0)*256 + threadIdx.x; i < D.n4; i += nb*256){
    float4 v = x4[i];
    union { u16 o[4]; uint2 u; } ou;
    float tt;
    tt = fminf(fmaxf(rintf(v.x / s), lo), 127.f); ou.o[0] = f2bf(tt);
    tt = fminf(fmaxf(rintf(v.y / s), lo), 127.f); ou.o[1] = f2bf(tt);
    tt = fminf(fmaxf(rintf(v.z / s), lo), 127.f); ou.o[2] = f2bf(tt);
    tt = fminf(fmaxf(rintf(v.w / s), lo), 127.f); ou.o[3] = f2bf(tt);
    ((uint2*)D.y)[i] = ou.u;
  }
}

// single-tensor quant (for attention output)
__global__ __launch_bounds__(256) void k_quant(const float* __restrict__ x,
    u16* __restrict__ y, int n4, const float* __restrict__ sc, int slot){
  const float s = fmaxf(sc[slot] / 128.0f, EPSF);
  const float4* x4 = (const float4*)x;
  for (int i = blockIdx.x*256 + threadIdx.x; i < n4; i += gridDim.x*256){
    float4 v = x4[i];
    union { u16 o[4]; uint2 u; } ou;
    float tt;
    tt = fminf(fmaxf(rintf(v.x / s), -128.f), 127.f); ou.o[0] = f2bf(tt);
    tt = fminf(fmaxf(rintf(v.y / s), -128.f), 127.f); ou.o[1] = f2bf(tt);
    tt = fminf(fmaxf(rintf(v.z / s), -128.f), 127.f); ou.o[2] = f2bf(tt);
    tt = fminf(fmaxf(rintf(v.w / s), -128.f), 127.f); ou.o[3] = f2bf(tt);
    ((uint2*)y)[i] = ou.u;
  }
}

// ---------------- GEMM: 128x128 tile, BK=64, 8 waves, 2-barrier loop + T2 swizzle ----
// swizzle: stored chunk c holds source chunk c ^ (row&7); read XORs the same way.
__device__ __forceinline__ void gemm_body(const u16* __restrict__ A,
    const u16* __restrict__ W, const float* __restrict__ bias,
    float* __restrict__ out, float s_b, int rowBase, int colBase,
    int* __restrict__ amax_out, u16 (*As)[64], u16 (*Bs)[64], float* red){
  const int tid = threadIdx.x;
  const int wid = tid >> 6, lane = tid & 63;
  const int wm = wid >> 2, wn = wid & 3;
  const int rr = lane & 15, g = lane >> 4;
  // staging: wave stages 8 rows/round; row&7 == lane>>3, so source swizzle is lane-only
  const int srow = wid*8 + (lane >> 3);
  const int sco  = ((lane & 7) ^ (lane >> 3)) << 3;
  const u16* Arow0 = &A[(size_t)(rowBase + srow)*KDIM + sco];
  const u16* Arow1 = &A[(size_t)(rowBase + 64 + srow)*KDIM + sco];
  const u16* Wrow0 = &W[(size_t)(colBase + srow)*KDIM + sco];
  const u16* Wrow1 = &W[(size_t)(colBase + 64 + srow)*KDIM + sco];
  f32x4 c[4][2] = {};
  int aoff[4][2], boff[2][2];
#pragma unroll
  for (int i = 0; i < 4; i++){
    int row = wm*64 + i*16 + rr;
#pragma unroll
    for (int h = 0; h < 2; h++)
      aoff[i][h] = row*64 + (((h*4 + g) ^ (row & 7)) << 3);
  }
#pragma unroll
  for (int j = 0; j < 2; j++){
    int row = wn*32 + j*16 + rr;
#pragma unroll
    for (int h = 0; h < 2; h++)
      boff[j][h] = row*64 + (((h*4 + g) ^ (row & 7)) << 3);
  }
  for (int k0 = 0; k0 < KDIM; k0 += 64){
    __syncthreads();
    GLOAD16(Arow0 + k0, &As[wid*8][0]);
    GLOAD16(Arow1 + k0, &As[64 + wid*8][0]);
    GLOAD16(Wrow0 + k0, &Bs[wid*8][0]);
    GLOAD16(Wrow1 + k0, &Bs[64 + wid*8][0]);
    __syncthreads();
#pragma unroll
    for (int h = 0; h < 2; h++){
      bf16x8 af[4], bfr[2];
#pragma unroll
      for (int i = 0; i < 4; i++) af[i]  = *(const bf16x8*)((const u16*)As + aoff[i][h]);
#pragma unroll
      for (int j = 0; j < 2; j++) bfr[j] = *(const bf16x8*)((const u16*)Bs + boff[j][h]);
#pragma unroll
      for (int i = 0; i < 4; i++)
#pragma unroll
        for (int j = 0; j < 2; j++)
          c[i][j] = MFMA16(af[i], bfr[j], c[i][j]);
    }
  }
  float lmax = 0.0f;
  const int r0 = (lane >> 4) * 4, ccol = lane & 15;
#pragma unroll
  for (int j = 0; j < 2; j++){
    int col = colBase + wn*32 + j*16 + ccol;
    float rb = rintf(bias[col] / s_b);
#pragma unroll
    for (int i = 0; i < 4; i++){
      int rowb = rowBase + wm*64 + i*16 + r0;
#pragma unroll
      for (int rI = 0; rI < 4; rI++){
        float y = s_b * (c[i][j][rI] + rb);
        out[(size_t)(rowb + rI)*NDIM + col] = y;
        lmax = fmaxf(lmax, fabsf(y));
      }
    }
  }
  lmax = wave_max(lmax);
  if (lane == 0) red[wid] = lmax;
  __syncthreads();
  if (tid == 0){
    float mm = red[0];
#pragma unroll
    for (int i2 = 1; i2 < 8; i2++) mm = fmaxf(mm, red[i2]);
    atomicMax(amax_out, __float_as_int(mm));
  }
}

// QKV projections fused: grid 768 (3 segs x 256 tiles), XCD-chunked swizzle
__global__ __launch_bounds__(512) void k_gemm3(const u16* __restrict__ Xall,
    const u16* __restrict__ Wall, const float* __restrict__ ball,
    float* __restrict__ Yall, const float* __restrict__ sc, int* __restrict__ sci){
  __shared__ u16 As[128][64];
  __shared__ u16 Bs[128][64];
  __shared__ float red[8];
  const int orig = blockIdx.x;
  const int xcd = orig & 7, sl = orig >> 3;          // sl in [0,96)
  const int seg = sl >> 5;                            // 0..2
  const int t2 = xcd*32 + (sl & 31);                  // 0..255
  const int by = t2 >> 3, bx = t2 & 7;
  const float s_x = fmaxf(sc[seg] / 128.0f, EPSF);
  const float s_w = fmaxf(sc[3 + seg] / 127.0f, EPSF);
  gemm_body(Xall + (size_t)seg*NTOK*KDIM, Wall + (size_t)seg*KDIM*NDIM,
            ball + seg*1024, Yall + (size_t)seg*NTOK*NDIM, s_x*s_w,
            by*128, bx*128, sci + 7 + seg, As, Bs, red);
}

// out-projection: grid 256
__global__ __launch_bounds__(512) void k_gemm1(const u16* __restrict__ A,
    const u16* __restrict__ W, const float* __restrict__ bias,
    float* __restrict__ out, const float* __restrict__ sc,
    int sx_slot, int sw_slot, int* __restrict__ amax_out){
  __shared__ u16 As[128][64];
  __shared__ u16 Bs[128][64];
  __shared__ float red[8];
  const int orig = blockIdx.x;
  const int t2 = (orig & 7)*32 + (orig >> 3);
  const int by = t2 >> 3, bx = t2 & 7;
  const float s_x = fmaxf(sc[sx_slot] / 128.0f, EPSF);
  const float s_w = fmaxf(sc[sw_slot] / 127.0f, EPSF);
  gemm_body(A, W, bias, out, s_x*s_w, by*128, bx*128, amax_out, As, Bs, red);
}

// q/k/v f32 (S,B,E) -> quantized head layouts: qh,kh [BH][S][DH], vt [BH][DH][S]
__global__ __launch_bounds__(256) void k_quant_heads(const float* __restrict__ qf,
    const float* __restrict__ kf, const float* __restrict__ vf,
    u16* __restrict__ qh, u16* __restrict__ kh, u16* __restrict__ vt,
    const float* __restrict__ sc){
  const float s_q = fmaxf((sc[7]*0.125f)/128.0f, EPSF);  // scale of q/sqrt(64)
  const float s_k = fmaxf(sc[8]/128.0f, EPSF);
  const float s_v = fmaxf(sc[9]/128.0f, EPSF);
  __shared__ u16 tile[64][80];
  const int bx = blockIdx.x;
  const int st = bx & 15, hh = (bx >> 4) & 15, b = bx >> 8;
  const int t = threadIdx.x;
  const int sl = t >> 2, dc = (t & 3) * 16;
  const size_t row = (size_t)(st*64 + sl)*BATCH + b;
  const size_t ibase = row*EMB + hh*DHEAD + dc;
  const int bh = b*NH + hh;
  float vq[16], vk[16], vv[16];
#pragma unroll
  for (int i = 0; i < 4; i++){
    *(float4*)&vq[i*4] = *(const float4*)&qf[ibase + i*4];
    *(float4*)&vk[i*4] = *(const float4*)&kf[ibase + i*4];
    *(float4*)&vv[i*4] = *(const float4*)&vf[ibase + i*4];
  }
  alignas(16) u16 oq[16], ok[16];
#pragma unroll
  for (int i = 0; i < 16; i++){
    float tq = fminf(fmaxf(rintf((vq[i]*0.125f)/s_q), -128.f), 127.f);
    float tk = fminf(fmaxf(rintf(vk[i]/s_k), -128.f), 127.f);
    float tv = fminf(fmaxf(rintf(vv[i]/s_v), -128.f), 127.f);
    oq[i] = f2bf(tq); ok[i] = f2bf(tk);
    tile[dc + i][sl] = f2bf(tv);
  }
  const size_t qoff = ((size_t)bh*S_LEN + st*64 + sl)*DHEAD + dc;
  *(bf16x8*)&qh[qoff]     = *(const bf16x8*)&oq[0];
  *(bf16x8*)&qh[qoff + 8] = *(const bf16x8*)&oq[8];
  *(bf16x8*)&kh[qoff]     = *(const bf16x8*)&ok[0];
  *(bf16x8*)&kh[qoff + 8] = *(const bf16x8*)&ok[8];
  __syncthreads();
  const int d = t >> 2, sc4 = (t & 3) * 16;
  alignas(16) u16 ov[16];
#pragma unroll
  for (int i = 0; i < 16; i++) ov[i] = tile[d][sc4 + i];
  const size_t voff = ((size_t)bh*DHEAD + d)*S_LEN + st*64 + sc4;
  *(bf16x8*)&vt[voff]     = *(const bf16x8*)&ov[0];
  *(bf16x8*)&vt[voff + 8] = *(const bf16x8*)&ov[8];
}

// attention pass 1: ONLINE softmax stats, barrier-free, K fragments direct from L2.
__global__ __launch_bounds__(256) void k_attn1(const u16* __restrict__ qh,
    const u16* __restrict__ kh, float* __restrict__ mrow, float* __restrict__ lrow,
    const float* __restrict__ sc, int* __restrict__ sci){
  const int orig = blockIdx.x;
  const int tile = (orig & 7) * 128 + (orig >> 3);   // XCD-chunked swizzle
  const int bhead = tile >> 4, q0 = (tile & 15) * 64;
  const int tid = threadIdx.x, w = tid >> 6, lane = tid & 63;
  const int rr = lane & 15, g = lane >> 4, kk = g * 8;
  const float s_q = fmaxf((sc[7]*0.125f)/128.0f, EPSF);
  const float s_k = fmaxf(sc[8]/128.0f, EPSF);
  const float s_qk = s_q * s_k;
  const u16* qbase = qh + ((size_t)bhead*S_LEN + q0 + w*16)*DHEAD;
  const u16* kbase = kh + (size_t)bhead*S_LEN*DHEAD;
  bf16x8 a0 = *(const bf16x8*)&qbase[rr*DHEAD + kk];
  bf16x8 a1 = *(const bf16x8*)&qbase[rr*DHEAD + 32 + kk];
  float m[4] = {-1e30f, -1e30f, -1e30f, -1e30f};
  float l[4] = {0.f, 0.f, 0.f, 0.f};
  for (int cch = 0; cch < 16; cch++){
    const int n0 = cch * 64;
    float sv[4][4];
#pragma unroll
    for (int nt = 0; nt < 4; nt++){
      const u16* kp = kbase + (size_t)(n0 + nt*16 + rr)*DHEAD + kk;
      bf16x8 b0 = *(const bf16x8*)kp;
      bf16x8 b1 = *(const bf16x8*)(kp + 32);
      f32x4 acc = {};
      acc = MFMA16(a0, b0, acc);
      acc = MFMA16(a1, b1, acc);
#pragma unroll
      for (int r = 0; r < 4; r++) sv[nt][r] = acc[r]*s_qk;
    }
#pragma unroll
    for (int r = 0; r < 4; r++){
      float cm = fmaxf(fmaxf(sv[0][r], sv[1][r]), fmaxf(sv[2][r], sv[3][r]));
      float mn = fmaxf(m[r], cm);
      l[r] *= EXP2F((m[r] - mn)*LOG2E);      // 1.0 when max unchanged
      m[r] = mn;
#pragma unroll
      for (int nt = 0; nt < 4; nt++)
        l[r] += EXP2F((sv[nt][r] - m[r])*LOG2E);
    }
  }
  // merge (m,l) across the 16 lanes of each column group
#pragma unroll
  for (int off = 1; off < 16; off <<= 1){
#pragma unroll
    for (int r = 0; r < 4; r++){
      float mo = __shfl_xor(m[r], off), lo = __shfl_xor(l[r], off);
      float mn = fmaxf(m[r], mo);
      l[r] = l[r]*EXP2F((m[r] - mn)*LOG2E) + lo*EXP2F((mo - mn)*LOG2E);
      m[r] = mn;
    }
  }
  if (rr == 0){
    int rowb = q0 + w*16 + g*4;
#pragma unroll
    for (int r = 0; r < 4; r++){
      mrow[(size_t)bhead*S_LEN + rowb + r] = m[r];
      lrow[(size_t)bhead*S_LEN + rowb + r] = l[r];
    }
  }
  // per-wave max of 1/l -> sci[13] (for s_a)
  float im = 0.0f;
#pragma unroll
  for (int r = 0; r < 4; r++) im = fmaxf(im, 1.0f / l[r]);
  im = wave_max(im);
  if (lane == 0) atomicMax(sci + 13, __float_as_int(im));
}

// attention pass 2: barrier-free; K/V fragments direct from L2; per-wave P in LDS.
__global__ __launch_bounds__(256) void k_attn2(const u16* __restrict__ qh,
    const u16* __restrict__ kh, const u16* __restrict__ vt,
    const float* __restrict__ mrow, const float* __restrict__ lrow,
    float* __restrict__ aout, const float* __restrict__ sc,
    const int* __restrict__ sci, int* __restrict__ amax_out){
  __shared__ u16 P[4][16][72];
  const int orig = blockIdx.x;
  const int tile = (orig & 7) * 128 + (orig >> 3);   // XCD-chunked swizzle
  const int bhead = tile >> 4, q0 = (tile & 15) * 64;
  const int tid = threadIdx.x, w = tid >> 6, lane = tid & 63;
  const int rr = lane & 15, g = lane >> 4, kk = g * 8;
  const float s_q = fmaxf((sc[7]*0.125f)/128.0f, EPSF);
  const float s_k = fmaxf(sc[8]/128.0f, EPSF);
  const float s_qk = s_q * s_k;
  const float s_v = fmaxf(sc[9]/128.0f, EPSF);
  const float s_a = fmaxf(__int_as_float(sci[13]) / 255.0f, EPSF);
  const float fac = s_a * s_v;
  const u16* qbase = qh + ((size_t)bhead*S_LEN + q0 + w*16)*DHEAD;
  const u16* kbase = kh + (size_t)bhead*S_LEN*DHEAD;
  const u16* vbase = vt + (size_t)bhead*DHEAD*S_LEN;
  bf16x8 a0 = *(const bf16x8*)&qbase[rr*DHEAD + kk];
  bf16x8 a1 = *(const bf16x8*)&qbase[rr*DHEAD + 32 + kk];
  float mr[4], inv[4];
  {
    int rowb = q0 + w*16 + g*4;
#pragma unroll
    for (int r = 0; r < 4; r++){
      mr[r]  = mrow[(size_t)bhead*S_LEN + rowb + r];
      inv[r] = 1.0f / (lrow[(size_t)bhead*S_LEN + rowb + r] * s_a);
    }
  }
  f32x4 cpv[4] = {};
  for (int cch = 0; cch < 16; cch++){
    const int n0 = cch * 64;
#pragma unroll
    for (int nt = 0; nt < 4; nt++){
      const u16* kp = kbase + (size_t)(n0 + nt*16 + rr)*DHEAD + kk;
      bf16x8 b0 = *(const bf16x8*)kp;
      bf16x8 b1 = *(const bf16x8*)(kp + 32);
      f32x4 acc = {};
      acc = MFMA16(a0, b0, acc);
      acc = MFMA16(a1, b1, acc);
#pragma unroll
      for (int r = 0; r < 4; r++){
        float e  = EXP2F((acc[r]*s_qk - mr[r])*LOG2E);
        float pq = fminf(rintf(e * inv[r]), 255.0f);
        P[w][g*4 + r][nt*16 + rr] = f2bf(pq);
      }
    }
    // PV: within-wave P dependency (lgkmcnt orders write->read; no barrier needed)
    bf16x8 pa0 = *(const bf16x8*)&P[w][rr][kk];
    bf16x8 pa1 = *(const bf16x8*)&P[w][rr][32 + kk];
#pragma unroll
    for (int f = 0; f < 4; f++){
      const u16* vp = vbase + (size_t)(f*16 + rr)*S_LEN + n0 + kk;
      bf16x8 v0 = *(const bf16x8*)vp;
      bf16x8 v1 = *(const bf16x8*)(vp + 32);
      cpv[f] = MFMA16(pa0, v0, cpv[f]);
      cpv[f] = MFMA16(pa1, v1, cpv[f]);
    }
  }
  const int b = bhead >> 4, hh = bhead & 15;
  float lmax = 0.0f;
#pragma unroll
  for (int f = 0; f < 4; f++){
    int d = f*16 + rr;
#pragma unroll
    for (int r = 0; r < 4; r++){
      int srow = q0 + w*16 + g*4 + r;
      float y = fac * cpv[f][r];
      aout[(size_t)(srow*BATCH + b)*EMB + hh*DHEAD + d] = y;
      lmax = fmaxf(lmax, fabsf(y));
    }
  }
  lmax = wave_max(lmax);
  if (lane == 0) atomicMax(amax_out, __float_as_int(lmax));
}

extern "C" void kernel_launch(void* const* d_in, const int* in_sizes, int n_in,
                              void* d_out, int out_size, void* d_ws, size_t ws_size,
                              hipStream_t stream){
  const float* query = (const float*)d_in[0];
  const float* key   = (const float*)d_in[1];
  const float* value = (const float*)d_in[2];
  const float* inW   = (const float*)d_in[3];
  const float* inB   = (const float*)d_in[4];
  const float* outW  = (const float*)d_in[5];
  const float* outB  = (const float*)d_in[6];
  float* out = (float*)d_out;

  char* ws = (char*)d_ws;
  float* sc  = (float*)ws;
  int*   sci = (int*)ws;
  u16* WQQ = (u16*)(ws + 256);
  u16* WKQ = WQQ + 1024*1024;
  u16* WVQ = WKQ + 1024*1024;
  u16* WOQ = WVQ + 1024*1024;
  u16* XQ  = WOQ + 1024*1024;          // 4096x1024 each (bf16 ints)
  u16* XK  = XQ + NTOK*1024;
  u16* XV  = XK + NTOK*1024;
  float* QF = (float*)(XV + NTOK*1024); // 4096x1024 f32 each
  float* KF = QF + NTOK*1024;
  float* VF = KF + NTOK*1024;
  float* MROW = VF + NTOK*1024;         // 64K floats
  float* LROW = MROW + BHEAD*S_LEN;
  // reuse (lifetimes are disjoint along the serial stream):
  u16* QH = XQ;  u16* KH = XK;  u16* VT = XV;   // proj-input quants dead after GEMMs
  float* AOUT = QF;                              // q f32 dead after k_quant_heads
  u16* AOQ = (u16*)KF;                           // k f32 dead after k_quant_heads

  AQTable tab;
  tab.d[0] = { query,             XQ,  NTOK*1024/4, 0, 128.f, -128.f };
  tab.d[1] = { key,               XK,  NTOK*1024/4, 1, 128.f, -128.f };
  tab.d[2] = { value,             XV,  NTOK*1024/4, 2, 128.f, -128.f };
  tab.d[3] = { inW,               WQQ, 1024*1024/4, 3, 127.f, -127.f };
  tab.d[4] = { inW + 1024*1024,   WKQ, 1024*1024/4, 4, 127.f, -127.f };
  tab.d[5] = { inW + 2*1024*1024, WVQ, 1024*1024/4, 5, 127.f, -127.f };
  tab.d[6] = { outW,              WOQ, 1024*1024/4, 6, 127.f, -127.f };

  k_zero<<<1, 64, 0, stream>>>(sc);
  k_absmax7<<<2048, 256, 0, stream>>>(tab, sci);
  k_quant7<<<2048, 256, 0, stream>>>(tab, sc);
  k_gemm3<<<768, 512, 0, stream>>>(XQ, WQQ, inB, QF, sc, sci);
  k_quant_heads<<<1024, 256, 0, stream>>>(QF, KF, VF, QH, KH, VT, sc);
  k_attn1<<<1024, 256, 0, stream>>>(QH, KH, MROW, LROW, sc, sci);
  k_attn2<<<1024, 256, 0, stream>>>(QH, KH, VT, MROW, LROW, AOUT, sc, sci, sci + 10);
  k_quant<<<1024, 256, 0, stream>>>(AOUT, AOQ, NTOK*1024/4, sc, 10);
  k_gemm1<<<256, 512, 0, stream>>>(AOQ, WOQ, outB, out, sc, 10, 6, sci + 12);
}

// Round 8
// 213.522 us; speedup vs baseline: 1.7781x; 1.7781x over previous
//
#include <hip/hip_runtime.h>
#include <stdint.h>

typedef unsigned short u16;
typedef __attribute__((ext_vector_type(8))) short bf16x8;
typedef __attribute__((ext_vector_type(4))) float f32x4;

#define S_LEN 1024
#define BATCH 4
#define EMB   1024
#define NH    16
#define DHEAD 64
#define BHEAD 64
#define NTOK  4096
#define KDIM  1024
#define NDIM  1024
#define EPSF  1e-8f
#define LOG2E 1.4426950408889634f

#define MFMA16(a,b,c) __builtin_amdgcn_mfma_f32_16x16x32_bf16((a),(b),(c),0,0,0)

#define GLOAD16(g, l) __builtin_amdgcn_global_load_lds( \
    (const __attribute__((address_space(1))) void*)(g), \
    (__attribute__((address_space(3))) void*)(l), 16, 0, 0)

#define EXP2F(x) __builtin_amdgcn_exp2f(x)

// values at all call sites are exact small integers (|v| <= 255): bf16 = top 16 bits
__device__ __forceinline__ u16 f2bf(float f){
  return (u16)(__float_as_uint(f) >> 16);
}

__device__ __forceinline__ float wave_max(float v){
#pragma unroll
  for (int off = 32; off > 0; off >>= 1) v = fmaxf(v, __shfl_xor(v, off));
  return v;
}

// ---------------- scale slots ----------------
// 0 amax_query 1 amax_key 2 amax_value 3 amax_Wq 4 amax_Wk 5 amax_Wv 6 amax_Wo
// 7 amax_qproj 8 amax_kproj 9 amax_vproj 10 amax_attnout 11 s_a 12 dummy 13 inv_l_max

__global__ void k_zero(float* sc){
  if (threadIdx.x < 16) sc[threadIdx.x] = 0.0f;
}

struct AQDesc { const float* x; u16* y; int n4; int slot; float qdiv; float lo; };
struct AQTable { AQDesc d[7]; };

// merged absmax over 7 tensors; grid = 2048 (3x512 for q/k/v, 4x128 for weights)
__global__ __launch_bounds__(256) void k_absmax7(AQTable t, int* __restrict__ sci){
  const int bid = blockIdx.x;
  int seg, b0, nb;
  if (bid < 1536){ seg = bid >> 9; b0 = seg << 9; nb = 512; }
  else { seg = 3 + ((bid - 1536) >> 7); b0 = 1536 + ((seg - 3) << 7); nb = 128; }
  const AQDesc D = t.d[seg];
  float m = 0.0f;
  const float4* x4 = (const float4*)D.x;
  for (int i = (bid - b0)*256 + threadIdx.x; i < D.n4; i += nb*256){
    float4 v = x4[i];
    m = fmaxf(m, fmaxf(fmaxf(fabsf(v.x), fabsf(v.y)), fmaxf(fabsf(v.z), fabsf(v.w))));
  }
  m = wave_max(m);
  __shared__ float red[4];
  int lane = threadIdx.x & 63, w = threadIdx.x >> 6;
  if (lane == 0) red[w] = m;
  __syncthreads();
  if (threadIdx.x == 0){
    float mm = fmaxf(fmaxf(red[0], red[1]), fmaxf(red[2], red[3]));
    atomicMax(sci + D.slot, __float_as_int(mm));
  }
}

// merged fake-quant of 7 tensors to integer grid stored as bf16 ints
__global__ __launch_bounds__(256) void k_quant7(AQTable t, const float* __restrict__ sc){
  const int bid = blockIdx.x;
  int seg, b0, nb;
  if (bid < 1536){ seg = bid >> 9; b0 = seg << 9; nb = 512; }
  else { seg = 3 + ((bid - 1536) >> 7); b0 = 1536 + ((seg - 3) << 7); nb = 128; }
  const AQDesc D = t.d[seg];
  const float s = fmaxf(sc[D.slot] / D.qdiv, EPSF);
  const float lo = D.lo;
  const float4* x4 = (const float4*)D.x;
  for (int i = (bid - b0)*256 + threadIdx.x; i < D.n4; i += nb*256){
    float4 v = x4[i];
    union { u16 o[4]; uint2 u; } ou;
    float tt;
    tt = fminf(fmaxf(rintf(v.x / s), lo), 127.f); ou.o[0] = f2bf(tt);
    tt = fminf(fmaxf(rintf(v.y / s), lo), 127.f); ou.o[1] = f2bf(tt);
    tt = fminf(fmaxf(rintf(v.z / s), lo), 127.f); ou.o[2] = f2bf(tt);
    tt = fminf(fmaxf(rintf(v.w / s), lo), 127.f); ou.o[3] = f2bf(tt);
    ((uint2*)D.y)[i] = ou.u;
  }
}

// single-tensor quant (for attention output)
__global__ __launch_bounds__(256) void k_quant(const float* __restrict__ x,
    u16* __restrict__ y, int n4, const float* __restrict__ sc, int slot){
  const float s = fmaxf(sc[slot] / 128.0f, EPSF);
  const float4* x4 = (const float4*)x;
  for (int i = blockIdx.x*256 + threadIdx.x; i < n4; i += gridDim.x*256){
    float4 v = x4[i];
    union { u16 o[4]; uint2 u; } ou;
    float tt;
    tt = fminf(fmaxf(rintf(v.x / s), -128.f), 127.f); ou.o[0] = f2bf(tt);
    tt = fminf(fmaxf(rintf(v.y / s), -128.f), 127.f); ou.o[1] = f2bf(tt);
    tt = fminf(fmaxf(rintf(v.z / s), -128.f), 127.f); ou.o[2] = f2bf(tt);
    tt = fminf(fmaxf(rintf(v.w / s), -128.f), 127.f); ou.o[3] = f2bf(tt);
    ((uint2*)y)[i] = ou.u;
  }
}

// ---------------- GEMM: 128x128 tile, BK=64, 8 waves, 2-barrier loop + T2 swizzle ----
// swizzle: stored chunk c holds source chunk c ^ (row&7); read XORs the same way.
__device__ __forceinline__ void gemm_body(const u16* __restrict__ A,
    const u16* __restrict__ W, const float* __restrict__ bias,
    float* __restrict__ out, float s_b, int rowBase, int colBase,
    int* __restrict__ amax_out, u16 (*As)[64], u16 (*Bs)[64], float* red){
  const int tid = threadIdx.x;
  const int wid = tid >> 6, lane = tid & 63;
  const int wm = wid >> 2, wn = wid & 3;
  const int rr = lane & 15, g = lane >> 4;
  // staging: wave stages 8 rows/round; row&7 == lane>>3, so source swizzle is lane-only
  const int srow = wid*8 + (lane >> 3);
  const int sco  = ((lane & 7) ^ (lane >> 3)) << 3;
  const u16* Arow0 = &A[(size_t)(rowBase + srow)*KDIM + sco];
  const u16* Arow1 = &A[(size_t)(rowBase + 64 + srow)*KDIM + sco];
  const u16* Wrow0 = &W[(size_t)(colBase + srow)*KDIM + sco];
  const u16* Wrow1 = &W[(size_t)(colBase + 64 + srow)*KDIM + sco];
  f32x4 c[4][2] = {};
  int aoff[4][2], boff[2][2];
#pragma unroll
  for (int i = 0; i < 4; i++){
    int row = wm*64 + i*16 + rr;
#pragma unroll
    for (int h = 0; h < 2; h++)
      aoff[i][h] = row*64 + (((h*4 + g) ^ (row & 7)) << 3);
  }
#pragma unroll
  for (int j = 0; j < 2; j++){
    int row = wn*32 + j*16 + rr;
#pragma unroll
    for (int h = 0; h < 2; h++)
      boff[j][h] = row*64 + (((h*4 + g) ^ (row & 7)) << 3);
  }
  for (int k0 = 0; k0 < KDIM; k0 += 64){
    __syncthreads();
    GLOAD16(Arow0 + k0, &As[wid*8][0]);
    GLOAD16(Arow1 + k0, &As[64 + wid*8][0]);
    GLOAD16(Wrow0 + k0, &Bs[wid*8][0]);
    GLOAD16(Wrow1 + k0, &Bs[64 + wid*8][0]);
    __syncthreads();
#pragma unroll
    for (int h = 0; h < 2; h++){
      bf16x8 af[4], bfr[2];
#pragma unroll
      for (int i = 0; i < 4; i++) af[i]  = *(const bf16x8*)((const u16*)As + aoff[i][h]);
#pragma unroll
      for (int j = 0; j < 2; j++) bfr[j] = *(const bf16x8*)((const u16*)Bs + boff[j][h]);
#pragma unroll
      for (int i = 0; i < 4; i++)
#pragma unroll
        for (int j = 0; j < 2; j++)
          c[i][j] = MFMA16(af[i], bfr[j], c[i][j]);
    }
  }
  float lmax = 0.0f;
  const int r0 = (lane >> 4) * 4, ccol = lane & 15;
#pragma unroll
  for (int j = 0; j < 2; j++){
    int col = colBase + wn*32 + j*16 + ccol;
    float rb = rintf(bias[col] / s_b);
#pragma unroll
    for (int i = 0; i < 4; i++){
      int rowb = rowBase + wm*64 + i*16 + r0;
#pragma unroll
      for (int rI = 0; rI < 4; rI++){
        float y = s_b * (c[i][j][rI] + rb);
        out[(size_t)(rowb + rI)*NDIM + col] = y;
        lmax = fmaxf(lmax, fabsf(y));
      }
    }
  }
  lmax = wave_max(lmax);
  if (lane == 0) red[wid] = lmax;
  __syncthreads();
  if (tid == 0){
    float mm = red[0];
#pragma unroll
    for (int i2 = 1; i2 < 8; i2++) mm = fmaxf(mm, red[i2]);
    atomicMax(amax_out, __float_as_int(mm));
  }
}

// QKV projections fused: grid 768 (3 segs x 256 tiles), XCD-chunked swizzle
__global__ __launch_bounds__(512) void k_gemm3(const u16* __restrict__ Xall,
    const u16* __restrict__ Wall, const float* __restrict__ ball,
    float* __restrict__ Yall, const float* __restrict__ sc, int* __restrict__ sci){
  __shared__ u16 As[128][64];
  __shared__ u16 Bs[128][64];
  __shared__ float red[8];
  const int orig = blockIdx.x;
  const int xcd = orig & 7, sl = orig >> 3;          // sl in [0,96)
  const int seg = sl >> 5;                            // 0..2
  const int t2 = xcd*32 + (sl & 31);                  // 0..255
  const int by = t2 >> 3, bx = t2 & 7;
  const float s_x = fmaxf(sc[seg] / 128.0f, EPSF);
  const float s_w = fmaxf(sc[3 + seg] / 127.0f, EPSF);
  gemm_body(Xall + (size_t)seg*NTOK*KDIM, Wall + (size_t)seg*KDIM*NDIM,
            ball + seg*1024, Yall + (size_t)seg*NTOK*NDIM, s_x*s_w,
            by*128, bx*128, sci + 7 + seg, As, Bs, red);
}

// out-projection: grid 256
__global__ __launch_bounds__(512) void k_gemm1(const u16* __restrict__ A,
    const u16* __restrict__ W, const float* __restrict__ bias,
    float* __restrict__ out, const float* __restrict__ sc,
    int sx_slot, int sw_slot, int* __restrict__ amax_out){
  __shared__ u16 As[128][64];
  __shared__ u16 Bs[128][64];
  __shared__ float red[8];
  const int orig = blockIdx.x;
  const int t2 = (orig & 7)*32 + (orig >> 3);
  const int by = t2 >> 3, bx = t2 & 7;
  const float s_x = fmaxf(sc[sx_slot] / 128.0f, EPSF);
  const float s_w = fmaxf(sc[sw_slot] / 127.0f, EPSF);
  gemm_body(A, W, bias, out, s_x*s_w, by*128, bx*128, amax_out, As, Bs, red);
}

// q/k/v f32 (S,B,E) -> quantized head layouts: qh,kh [BH][S][DH], vt [BH][DH][S]
__global__ __launch_bounds__(256) void k_quant_heads(const float* __restrict__ qf,
    const float* __restrict__ kf, const float* __restrict__ vf,
    u16* __restrict__ qh, u16* __restrict__ kh, u16* __restrict__ vt,
    const float* __restrict__ sc){
  const float s_q = fmaxf((sc[7]*0.125f)/128.0f, EPSF);  // scale of q/sqrt(64)
  const float s_k = fmaxf(sc[8]/128.0f, EPSF);
  const float s_v = fmaxf(sc[9]/128.0f, EPSF);
  __shared__ u16 tile[64][80];
  const int bx = blockIdx.x;
  const int st = bx & 15, hh = (bx >> 4) & 15, b = bx >> 8;
  const int t = threadIdx.x;
  const int sl = t >> 2, dc = (t & 3) * 16;
  const size_t row = (size_t)(st*64 + sl)*BATCH + b;
  const size_t ibase = row*EMB + hh*DHEAD + dc;
  const int bh = b*NH + hh;
  float vq[16], vk[16], vv[16];
#pragma unroll
  for (int i = 0; i < 4; i++){
    *(float4*)&vq[i*4] = *(const float4*)&qf[ibase + i*4];
    *(float4*)&vk[i*4] = *(const float4*)&kf[ibase + i*4];
    *(float4*)&vv[i*4] = *(const float4*)&vf[ibase + i*4];
  }
  alignas(16) u16 oq[16], ok[16];
#pragma unroll
  for (int i = 0; i < 16; i++){
    float tq = fminf(fmaxf(rintf((vq[i]*0.125f)/s_q), -128.f), 127.f);
    float tk = fminf(fmaxf(rintf(vk[i]/s_k), -128.f), 127.f);
    float tv = fminf(fmaxf(rintf(vv[i]/s_v), -128.f), 127.f);
    oq[i] = f2bf(tq); ok[i] = f2bf(tk);
    tile[dc + i][sl] = f2bf(tv);
  }
  const size_t qoff = ((size_t)bh*S_LEN + st*64 + sl)*DHEAD + dc;
  *(bf16x8*)&qh[qoff]     = *(const bf16x8*)&oq[0];
  *(bf16x8*)&qh[qoff + 8] = *(const bf16x8*)&oq[8];
  *(bf16x8*)&kh[qoff]     = *(const bf16x8*)&ok[0];
  *(bf16x8*)&kh[qoff + 8] = *(const bf16x8*)&ok[8];
  __syncthreads();
  const int d = t >> 2, sc4 = (t & 3) * 16;
  alignas(16) u16 ov[16];
#pragma unroll
  for (int i = 0; i < 16; i++) ov[i] = tile[d][sc4 + i];
  const size_t voff = ((size_t)bh*DHEAD + d)*S_LEN + st*64 + sc4;
  *(bf16x8*)&vt[voff]     = *(const bf16x8*)&ov[0];
  *(bf16x8*)&vt[voff + 8] = *(const bf16x8*)&ov[8];
}

// attention pass 1: ONLINE softmax stats (single pass), exp2-native.
// Also folds block-max of 1/l into sci[13].
__global__ __launch_bounds__(256) void k_attn1(const u16* __restrict__ qh,
    const u16* __restrict__ kh, float* __restrict__ mrow, float* __restrict__ lrow,
    const float* __restrict__ sc, int* __restrict__ sci){
  __shared__ u16 Ks[64][64];
  __shared__ float red2[4];
  const int orig = blockIdx.x;
  const int tile = (orig & 7) * 128 + (orig >> 3);   // XCD-chunked swizzle
  const int bhead = tile >> 4, q0 = (tile & 15) * 64;
  const int tid = threadIdx.x, w = tid >> 6, lane = tid & 63;
  const int rr = lane & 15, g = lane >> 4, kk = g * 8;
  const int lr3 = lane >> 3, lc = lane & 7;
  const float s_q = fmaxf((sc[7]*0.125f)/128.0f, EPSF);
  const float s_k = fmaxf(sc[8]/128.0f, EPSF);
  const float s_qk = s_q * s_k;
  const u16* qbase = qh + ((size_t)bhead*S_LEN + q0 + w*16)*DHEAD;
  const u16* kbase = kh + (size_t)bhead*S_LEN*DHEAD;
  bf16x8 a0 = *(const bf16x8*)&qbase[rr*DHEAD + kk];
  bf16x8 a1 = *(const bf16x8*)&qbase[rr*DHEAD + 32 + kk];
  float m[4] = {-1e30f, -1e30f, -1e30f, -1e30f};
  float l[4] = {0.f, 0.f, 0.f, 0.f};
  for (int cch = 0; cch < 16; cch++){
    const int n0 = cch * 64;
    __syncthreads();
#pragma unroll
    for (int i = 0; i < 2; i++){
      int r = w*16 + i*8 + lr3;
      GLOAD16(&kbase[(size_t)(n0 + r)*DHEAD + ((lc ^ (r & 7)) << 3)], &Ks[w*16 + i*8][0]);
    }
    __syncthreads();
    float sv[4][4];
#pragma unroll
    for (int nt = 0; nt < 4; nt++){
      int row = nt*16 + rr;
      bf16x8 b0 = *(const bf16x8*)((const u16*)Ks + row*64 + (((g    ) ^ (row & 7)) << 3));
      bf16x8 b1 = *(const bf16x8*)((const u16*)Ks + row*64 + (((4 + g) ^ (row & 7)) << 3));
      f32x4 acc = {};
      acc = MFMA16(a0, b0, acc);
      acc = MFMA16(a1, b1, acc);
#pragma unroll
      for (int r = 0; r < 4; r++) sv[nt][r] = acc[r]*s_qk;
    }
#pragma unroll
    for (int r = 0; r < 4; r++){
      float cm = fmaxf(fmaxf(sv[0][r], sv[1][r]), fmaxf(sv[2][r], sv[3][r]));
      float mn = fmaxf(m[r], cm);
      l[r] *= EXP2F((m[r] - mn)*LOG2E);      // 1.0 when max unchanged
      m[r] = mn;
#pragma unroll
      for (int nt = 0; nt < 4; nt++)
        l[r] += EXP2F((sv[nt][r] - m[r])*LOG2E);
    }
  }
  // merge (m,l) across the 16 lanes of each column group
#pragma unroll
  for (int off = 1; off < 16; off <<= 1){
#pragma unroll
    for (int r = 0; r < 4; r++){
      float mo = __shfl_xor(m[r], off), lo = __shfl_xor(l[r], off);
      float mn = fmaxf(m[r], mo);
      l[r] = l[r]*EXP2F((m[r] - mn)*LOG2E) + lo*EXP2F((mo - mn)*LOG2E);
      m[r] = mn;
    }
  }
  if (rr == 0){
    int rowb = q0 + w*16 + g*4;
#pragma unroll
    for (int r = 0; r < 4; r++){
      mrow[(size_t)bhead*S_LEN + rowb + r] = m[r];
      lrow[(size_t)bhead*S_LEN + rowb + r] = l[r];
    }
  }
  // block max of 1/l -> sci[13] (for s_a)
  float im = 0.0f;
#pragma unroll
  for (int r = 0; r < 4; r++) im = fmaxf(im, 1.0f / l[r]);
  im = wave_max(im);
  if (lane == 0) red2[w] = im;
  __syncthreads();
  if (tid == 0){
    float mm = fmaxf(fmaxf(red2[0], red2[1]), fmaxf(red2[2], red2[3]));
    atomicMax(sci + 13, __float_as_int(mm));
  }
}

__global__ void k_sa_final(float* sc, const int* sci){
  if (threadIdx.x == 0)
    sc[11] = fmaxf(__int_as_float(sci[13]) / 255.0f, EPSF);
}

// attention pass 2: recompute scores (bit-identical acc), quantize P, PV via MFMA
__global__ __launch_bounds__(256) void k_attn2(const u16* __restrict__ qh,
    const u16* __restrict__ kh, const u16* __restrict__ vt,
    const float* __restrict__ mrow, const float* __restrict__ lrow,
    float* __restrict__ aout, const float* __restrict__ sc, int* __restrict__ amax_out){
  __shared__ u16 Ks[64][64];
  __shared__ u16 Vs[64][64];
  __shared__ u16 P[4][16][72];
  __shared__ float red[4];
  const int orig = blockIdx.x;
  const int tile = (orig & 7) * 128 + (orig >> 3);   // XCD-chunked swizzle
  const int bhead = tile >> 4, q0 = (tile & 15) * 64;
  const int tid = threadIdx.x, w = tid >> 6, lane = tid & 63;
  const int rr = lane & 15, g = lane >> 4, kk = g * 8;
  const int lr3 = lane >> 3, lc = lane & 7;
  const float s_q = fmaxf((sc[7]*0.125f)/128.0f, EPSF);
  const float s_k = fmaxf(sc[8]/128.0f, EPSF);
  const float s_qk = s_q * s_k;
  const float s_v = fmaxf(sc[9]/128.0f, EPSF);
  const float s_a = sc[11];
  const float fac = s_a * s_v;
  const u16* qbase = qh + ((size_t)bhead*S_LEN + q0 + w*16)*DHEAD;
  const u16* kbase = kh + (size_t)bhead*S_LEN*DHEAD;
  const u16* vbase = vt + (size_t)bhead*DHEAD*S_LEN;
  bf16x8 a0 = *(const bf16x8*)&qbase[rr*DHEAD + kk];
  bf16x8 a1 = *(const bf16x8*)&qbase[rr*DHEAD + 32 + kk];
  float mr[4], inv[4];
  {
    int rowb = q0 + w*16 + g*4;
#pragma unroll
    for (int r = 0; r < 4; r++){
      mr[r]  = mrow[(size_t)bhead*S_LEN + rowb + r];
      inv[r] = 1.0f / (lrow[(size_t)bhead*S_LEN + rowb + r] * s_a);
    }
  }
  f32x4 cpv[4] = {};
  for (int cch = 0; cch < 16; cch++){
    const int n0 = cch * 64;
    __syncthreads();
#pragma unroll
    for (int i = 0; i < 2; i++){
      int r = w*16 + i*8 + lr3;
      GLOAD16(&kbase[(size_t)(n0 + r)*DHEAD + ((lc ^ (r & 7)) << 3)], &Ks[w*16 + i*8][0]);
      int d = w*16 + i*8 + lr3;
      GLOAD16(&vbase[(size_t)d*S_LEN + n0 + ((lc ^ (d & 7)) << 3)], &Vs[w*16 + i*8][0]);
    }
    __syncthreads();
#pragma unroll
    for (int nt = 0; nt < 4; nt++){
      int row = nt*16 + rr;
      bf16x8 b0 = *(const bf16x8*)((const u16*)Ks + row*64 + (((g    ) ^ (row & 7)) << 3));
      bf16x8 b1 = *(const bf16x8*)((const u16*)Ks + row*64 + (((4 + g) ^ (row & 7)) << 3));
      f32x4 acc = {};
      acc = MFMA16(a0, b0, acc);
      acc = MFMA16(a1, b1, acc);
#pragma unroll
      for (int r = 0; r < 4; r++){
        float e  = EXP2F((acc[r]*s_qk - mr[r])*LOG2E);
        float pq = fminf(rintf(e * inv[r]), 255.0f);
        P[w][g*4 + r][nt*16 + rr] = f2bf(pq);
      }
    }
    // PV: within-wave P dependency (compiler inserts lgkmcnt wait; no barrier needed)
    bf16x8 pa0 = *(const bf16x8*)&P[w][rr][kk];
    bf16x8 pa1 = *(const bf16x8*)&P[w][rr][32 + kk];
#pragma unroll
    for (int f = 0; f < 4; f++){
      int row = f*16 + rr;
      bf16x8 v0 = *(const bf16x8*)((const u16*)Vs + row*64 + (((g    ) ^ (row & 7)) << 3));
      bf16x8 v1 = *(const bf16x8*)((const u16*)Vs + row*64 + (((4 + g) ^ (row & 7)) << 3));
      cpv[f] = MFMA16(pa0, v0, cpv[f]);
      cpv[f] = MFMA16(pa1, v1, cpv[f]);
    }
  }
  const int b = bhead >> 4, hh = bhead & 15;
  float lmax = 0.0f;
#pragma unroll
  for (int f = 0; f < 4; f++){
    int d = f*16 + rr;
#pragma unroll
    for (int r = 0; r < 4; r++){
      int srow = q0 + w*16 + g*4 + r;
      float y = fac * cpv[f][r];
      aout[(size_t)(srow*BATCH + b)*EMB + hh*DHEAD + d] = y;
      lmax = fmaxf(lmax, fabsf(y));
    }
  }
  lmax = wave_max(lmax);
  __syncthreads();
  if (lane == 0) red[w] = lmax;
  __syncthreads();
  if (tid == 0){
    float mm = fmaxf(fmaxf(red[0], red[1]), fmaxf(red[2], red[3]));
    atomicMax(amax_out, __float_as_int(mm));
  }
}

extern "C" void kernel_launch(void* const* d_in, const int* in_sizes, int n_in,
                              void* d_out, int out_size, void* d_ws, size_t ws_size,
                              hipStream_t stream){
  const float* query = (const float*)d_in[0];
  const float* key   = (const float*)d_in[1];
  const float* value = (const float*)d_in[2];
  const float* inW   = (const float*)d_in[3];
  const float* inB   = (const float*)d_in[4];
  const float* outW  = (const float*)d_in[5];
  const float* outB  = (const float*)d_in[6];
  float* out = (float*)d_out;

  char* ws = (char*)d_ws;
  float* sc  = (float*)ws;
  int*   sci = (int*)ws;
  u16* WQQ = (u16*)(ws + 256);
  u16* WKQ = WQQ + 1024*1024;
  u16* WVQ = WKQ + 1024*1024;
  u16* WOQ = WVQ + 1024*1024;
  u16* XQ  = WOQ + 1024*1024;          // 4096x1024 each (bf16 ints)
  u16* XK  = XQ + NTOK*1024;
  u16* XV  = XK + NTOK*1024;
  float* QF = (float*)(XV + NTOK*1024); // 4096x1024 f32 each
  float* KF = QF + NTOK*1024;
  float* VF = KF + NTOK*1024;
  float* MROW = VF + NTOK*1024;         // 64K floats
  float* LROW = MROW + BHEAD*S_LEN;
  // reuse (lifetimes are disjoint along the serial stream):
  u16* QH = XQ;  u16* KH = XK;  u16* VT = XV;   // proj-input quants dead after GEMMs
  float* AOUT = QF;                              // q f32 dead after k_quant_heads
  u16* AOQ = (u16*)KF;                           // k f32 dead after k_quant_heads

  AQTable tab;
  tab.d[0] = { query,             XQ,  NTOK*1024/4, 0, 128.f, -128.f };
  tab.d[1] = { key,               XK,  NTOK*1024/4, 1, 128.f, -128.f };
  tab.d[2] = { value,             XV,  NTOK*1024/4, 2, 128.f, -128.f };
  tab.d[3] = { inW,               WQQ, 1024*1024/4, 3, 127.f, -127.f };
  tab.d[4] = { inW + 1024*1024,   WKQ, 1024*1024/4, 4, 127.f, -127.f };
  tab.d[5] = { inW + 2*1024*1024, WVQ, 1024*1024/4, 5, 127.f, -127.f };
  tab.d[6] = { outW,              WOQ, 1024*1024/4, 6, 127.f, -127.f };

  k_zero<<<1, 64, 0, stream>>>(sc);
  k_absmax7<<<2048, 256, 0, stream>>>(tab, sci);
  k_quant7<<<2048, 256, 0, stream>>>(tab, sc);
  k_gemm3<<<768, 512, 0, stream>>>(XQ, WQQ, inB, QF, sc, sci);
  k_quant_heads<<<1024, 256, 0, stream>>>(QF, KF, VF, QH, KH, VT, sc);
  k_attn1<<<1024, 256, 0, stream>>>(QH, KH, MROW, LROW, sc, sci);
  k_sa_final<<<1, 64, 0, stream>>>(sc, sci);
  k_attn2<<<1024, 256, 0, stream>>>(QH, KH, VT, MROW, LROW, AOUT, sc, sci + 10);
  k_quant<<<1024, 256, 0, stream>>>(AOUT, AOQ, NTOK*1024/4, sc, 10);
  k_gemm1<<<256, 512, 0, stream>>>(AOQ, WOQ, outB, out, sc, 10, 6, sci + 12);
}

// Round 9
// 187.718 us; speedup vs baseline: 2.0225x; 1.1375x over previous
//
#include <hip/hip_runtime.h>
#include <stdint.h>

typedef unsigned short u16;
typedef signed char i8;
typedef unsigned char u8;
typedef __attribute__((ext_vector_type(8))) short bf16x8;
typedef __attribute__((ext_vector_type(4))) float f32x4;
typedef __attribute__((ext_vector_type(4))) int i32x4;

#define S_LEN 1024
#define BATCH 4
#define EMB   1024
#define NH    16
#define DHEAD 64
#define BHEAD 64
#define NTOK  4096
#define KDIM  1024
#define NDIM  1024
#define EPSF  1e-8f
#define LOG2E 1.4426950408889634f

#define MFMA16(a,b,c)  __builtin_amdgcn_mfma_f32_16x16x32_bf16((a),(b),(c),0,0,0)
#define MFMAI8(a,b,c)  __builtin_amdgcn_mfma_i32_16x16x64_i8((a),(b),(c),0,0,0)

#define GLOAD16(g, l) __builtin_amdgcn_global_load_lds( \
    (const __attribute__((address_space(1))) void*)(g), \
    (__attribute__((address_space(3))) void*)(l), 16, 0, 0)

#define EXP2F(x) __builtin_amdgcn_exp2f(x)

// values at all call sites are exact small integers (|v| <= 255): bf16 = top 16 bits
__device__ __forceinline__ u16 f2bf(float f){
  return (u16)(__float_as_uint(f) >> 16);
}

__device__ __forceinline__ unsigned pack4(float a, float b, float c, float d){
  int qa = (int)a, qb = (int)b, qc = (int)c, qd = (int)d;
  return (unsigned)(qa & 255) | ((unsigned)(qb & 255) << 8) |
         ((unsigned)(qc & 255) << 16) | ((unsigned)(qd & 255) << 24);
}

__device__ __forceinline__ float wave_max(float v){
#pragma unroll
  for (int off = 32; off > 0; off >>= 1) v = fmaxf(v, __shfl_xor(v, off));
  return v;
}

// ---------------- scale slots ----------------
// 0 amax_query 1 amax_key 2 amax_value 3 amax_Wq 4 amax_Wk 5 amax_Wv 6 amax_Wo
// 7 amax_qproj 8 amax_kproj 9 amax_vproj 10 amax_attnout 11 s_a 12 dummy 13 inv_l_max

__global__ void k_zero(float* sc){
  if (threadIdx.x < 16) sc[threadIdx.x] = 0.0f;
}

struct AQDesc { const float* x; u8* y; int n4; int slot; float qdiv; float lo; };
struct AQTable { AQDesc d[7]; };

// merged absmax over 7 tensors; grid = 2048 (3x512 for q/k/v, 4x128 for weights)
__global__ __launch_bounds__(256) void k_absmax7(AQTable t, int* __restrict__ sci){
  const int bid = blockIdx.x;
  int seg, b0, nb;
  if (bid < 1536){ seg = bid >> 9; b0 = seg << 9; nb = 512; }
  else { seg = 3 + ((bid - 1536) >> 7); b0 = 1536 + ((seg - 3) << 7); nb = 128; }
  const AQDesc D = t.d[seg];
  float m = 0.0f;
  const float4* x4 = (const float4*)D.x;
  for (int i = (bid - b0)*256 + threadIdx.x; i < D.n4; i += nb*256){
    float4 v = x4[i];
    m = fmaxf(m, fmaxf(fmaxf(fabsf(v.x), fabsf(v.y)), fmaxf(fabsf(v.z), fabsf(v.w))));
  }
  m = wave_max(m);
  __shared__ float red[4];
  int lane = threadIdx.x & 63, w = threadIdx.x >> 6;
  if (lane == 0) red[w] = m;
  __syncthreads();
  if (threadIdx.x == 0){
    float mm = fmaxf(fmaxf(red[0], red[1]), fmaxf(red[2], red[3]));
    atomicMax(sci + D.slot, __float_as_int(mm));
  }
}

// merged fake-quant of 7 tensors to int8 grid
__global__ __launch_bounds__(256) void k_quant7(AQTable t, const float* __restrict__ sc){
  const int bid = blockIdx.x;
  int seg, b0, nb;
  if (bid < 1536){ seg = bid >> 9; b0 = seg << 9; nb = 512; }
  else { seg = 3 + ((bid - 1536) >> 7); b0 = 1536 + ((seg - 3) << 7); nb = 128; }
  const AQDesc D = t.d[seg];
  const float s = fmaxf(sc[D.slot] / D.qdiv, EPSF);
  const float lo = D.lo;
  const float4* x4 = (const float4*)D.x;
  unsigned* y4 = (unsigned*)D.y;
  for (int i = (bid - b0)*256 + threadIdx.x; i < D.n4; i += nb*256){
    float4 v = x4[i];
    float t0 = fminf(fmaxf(rintf(v.x / s), lo), 127.f);
    float t1 = fminf(fmaxf(rintf(v.y / s), lo), 127.f);
    float t2 = fminf(fmaxf(rintf(v.z / s), lo), 127.f);
    float t3 = fminf(fmaxf(rintf(v.w / s), lo), 127.f);
    y4[i] = pack4(t0, t1, t2, t3);
  }
}

// single-tensor quant to int8 (attention output)
__global__ __launch_bounds__(256) void k_quant(const float* __restrict__ x,
    u8* __restrict__ y, int n4, const float* __restrict__ sc, int slot){
  const float s = fmaxf(sc[slot] / 128.0f, EPSF);
  const float4* x4 = (const float4*)x;
  unsigned* y4 = (unsigned*)y;
  for (int i = blockIdx.x*256 + threadIdx.x; i < n4; i += gridDim.x*256){
    float4 v = x4[i];
    float t0 = fminf(fmaxf(rintf(v.x / s), -128.f), 127.f);
    float t1 = fminf(fmaxf(rintf(v.y / s), -128.f), 127.f);
    float t2 = fminf(fmaxf(rintf(v.z / s), -128.f), 127.f);
    float t3 = fminf(fmaxf(rintf(v.w / s), -128.f), 127.f);
    y4[i] = pack4(t0, t1, t2, t3);
  }
}

// ---------------- GEMM: 128x128 tile, BK=128 int8, 8 waves, 2-barrier + swizzle ----
// rows are 128 B = 8 chunks of 16 B; stored chunk c' = c ^ (row&7) (involution both sides)
__device__ __forceinline__ void gemm_body(const i8* __restrict__ A,
    const i8* __restrict__ W, const float* __restrict__ bias,
    float* __restrict__ out, float s_b, int rowBase, int colBase,
    int* __restrict__ amax_out, i8 (*As)[128], i8 (*Bs)[128], float* red){
  const int tid = threadIdx.x;
  const int wid = tid >> 6, lane = tid & 63;
  const int wm = wid >> 2, wn = wid & 3;
  const int rr = lane & 15, g = lane >> 4;
  // staging: wave stages 8 rows/call; row&7 == lane>>3 so source swizzle is lane-only
  const int srow = wid*8 + (lane >> 3);
  const int sco  = ((lane & 7) ^ (lane >> 3)) << 4;
  const i8* Arow0 = &A[(size_t)(rowBase + srow)*KDIM + sco];
  const i8* Arow1 = &A[(size_t)(rowBase + 64 + srow)*KDIM + sco];
  const i8* Wrow0 = &W[(size_t)(colBase + srow)*KDIM + sco];
  const i8* Wrow1 = &W[(size_t)(colBase + 64 + srow)*KDIM + sco];
  i32x4 c[4][2] = {};
  int aoff[4][2], boff[2][2];
#pragma unroll
  for (int i = 0; i < 4; i++){
    int row = wm*64 + i*16 + rr;
#pragma unroll
    for (int h = 0; h < 2; h++)
      aoff[i][h] = row*128 + (((h*4 + g) ^ (row & 7)) << 4);
  }
#pragma unroll
  for (int j = 0; j < 2; j++){
    int row = wn*32 + j*16 + rr;
#pragma unroll
    for (int h = 0; h < 2; h++)
      boff[j][h] = row*128 + (((h*4 + g) ^ (row & 7)) << 4);
  }
  for (int k0 = 0; k0 < KDIM; k0 += 128){
    __syncthreads();
    GLOAD16(Arow0 + k0, &As[wid*8][0]);
    GLOAD16(Arow1 + k0, &As[64 + wid*8][0]);
    GLOAD16(Wrow0 + k0, &Bs[wid*8][0]);
    GLOAD16(Wrow1 + k0, &Bs[64 + wid*8][0]);
    __syncthreads();
#pragma unroll
    for (int h = 0; h < 2; h++){
      i32x4 af[4], bfr[2];
#pragma unroll
      for (int i = 0; i < 4; i++) af[i]  = *(const i32x4*)((const i8*)As + aoff[i][h]);
#pragma unroll
      for (int j = 0; j < 2; j++) bfr[j] = *(const i32x4*)((const i8*)Bs + boff[j][h]);
#pragma unroll
      for (int i = 0; i < 4; i++)
#pragma unroll
        for (int j = 0; j < 2; j++)
          c[i][j] = MFMAI8(af[i], bfr[j], c[i][j]);
    }
  }
  float lmax = 0.0f;
  const int r0 = (lane >> 4) * 4, ccol = lane & 15;
#pragma unroll
  for (int j = 0; j < 2; j++){
    int col = colBase + wn*32 + j*16 + ccol;
    float rb = rintf(bias[col] / s_b);
#pragma unroll
    for (int i = 0; i < 4; i++){
      int rowb = rowBase + wm*64 + i*16 + r0;
#pragma unroll
      for (int rI = 0; rI < 4; rI++){
        float y = s_b * ((float)c[i][j][rI] + rb);
        out[(size_t)(rowb + rI)*NDIM + col] = y;
        lmax = fmaxf(lmax, fabsf(y));
      }
    }
  }
  lmax = wave_max(lmax);
  if (lane == 0) red[wid] = lmax;
  __syncthreads();
  if (tid == 0){
    float mm = red[0];
#pragma unroll
    for (int i2 = 1; i2 < 8; i2++) mm = fmaxf(mm, red[i2]);
    atomicMax(amax_out, __float_as_int(mm));
  }
}

// QKV projections fused: grid 768 (3 segs x 256 tiles), XCD-chunked swizzle
__global__ __launch_bounds__(512) void k_gemm3(const i8* __restrict__ Xall,
    const i8* __restrict__ Wall, const float* __restrict__ ball,
    float* __restrict__ Yall, const float* __restrict__ sc, int* __restrict__ sci){
  __shared__ i8 As[128][128];
  __shared__ i8 Bs[128][128];
  __shared__ float red[8];
  const int orig = blockIdx.x;
  const int xcd = orig & 7, sl = orig >> 3;          // sl in [0,96)
  const int seg = sl >> 5;                            // 0..2
  const int t2 = xcd*32 + (sl & 31);                  // 0..255
  const int by = t2 >> 3, bx = t2 & 7;
  const float s_x = fmaxf(sc[seg] / 128.0f, EPSF);
  const float s_w = fmaxf(sc[3 + seg] / 127.0f, EPSF);
  gemm_body(Xall + (size_t)seg*NTOK*KDIM, Wall + (size_t)seg*KDIM*NDIM,
            ball + seg*1024, Yall + (size_t)seg*NTOK*NDIM, s_x*s_w,
            by*128, bx*128, sci + 7 + seg, As, Bs, red);
}

// out-projection: grid 256
__global__ __launch_bounds__(512) void k_gemm1(const i8* __restrict__ A,
    const i8* __restrict__ W, const float* __restrict__ bias,
    float* __restrict__ out, const float* __restrict__ sc,
    int sx_slot, int sw_slot, int* __restrict__ amax_out){
  __shared__ i8 As[128][128];
  __shared__ i8 Bs[128][128];
  __shared__ float red[8];
  const int orig = blockIdx.x;
  const int t2 = (orig & 7)*32 + (orig >> 3);
  const int by = t2 >> 3, bx = t2 & 7;
  const float s_x = fmaxf(sc[sx_slot] / 128.0f, EPSF);
  const float s_w = fmaxf(sc[sw_slot] / 127.0f, EPSF);
  gemm_body(A, W, bias, out, s_x*s_w, by*128, bx*128, amax_out, As, Bs, red);
}

// q/k/v f32 (S,B,E) -> qh,kh int8 [BH][S][DH]; vt bf16-int [BH][DH][S]
__global__ __launch_bounds__(256) void k_quant_heads(const float* __restrict__ qf,
    const float* __restrict__ kf, const float* __restrict__ vf,
    i8* __restrict__ qh, i8* __restrict__ kh, u16* __restrict__ vt,
    const float* __restrict__ sc){
  const float s_q = fmaxf((sc[7]*0.125f)/128.0f, EPSF);  // scale of q/sqrt(64)
  const float s_k = fmaxf(sc[8]/128.0f, EPSF);
  const float s_v = fmaxf(sc[9]/128.0f, EPSF);
  __shared__ u16 tile[64][80];
  const int bx = blockIdx.x;
  const int st = bx & 15, hh = (bx >> 4) & 15, b = bx >> 8;
  const int t = threadIdx.x;
  const int sl = t >> 2, dc = (t & 3) * 16;
  const size_t row = (size_t)(st*64 + sl)*BATCH + b;
  const size_t ibase = row*EMB + hh*DHEAD + dc;
  const int bh = b*NH + hh;
  float vq[16], vk[16], vv[16];
#pragma unroll
  for (int i = 0; i < 4; i++){
    *(float4*)&vq[i*4] = *(const float4*)&qf[ibase + i*4];
    *(float4*)&vk[i*4] = *(const float4*)&kf[ibase + i*4];
    *(float4*)&vv[i*4] = *(const float4*)&vf[ibase + i*4];
  }
  alignas(16) i8 oq[16], ok[16];
#pragma unroll
  for (int i = 0; i < 16; i++){
    float tq = fminf(fmaxf(rintf((vq[i]*0.125f)/s_q), -128.f), 127.f);
    float tk = fminf(fmaxf(rintf(vk[i]/s_k), -128.f), 127.f);
    float tv = fminf(fmaxf(rintf(vv[i]/s_v), -128.f), 127.f);
    oq[i] = (i8)(int)tq; ok[i] = (i8)(int)tk;
    tile[dc + i][sl] = f2bf(tv);
  }
  const size_t qoff = ((size_t)bh*S_LEN + st*64 + sl)*DHEAD + dc;
  *(int4*)&qh[qoff] = *(const int4*)&oq[0];
  *(int4*)&kh[qoff] = *(const int4*)&ok[0];
  __syncthreads();
  const int d = t >> 2, sc4 = (t & 3) * 16;
  alignas(16) u16 ov[16];
#pragma unroll
  for (int i = 0; i < 16; i++) ov[i] = tile[d][sc4 + i];
  const size_t voff = ((size_t)bh*DHEAD + d)*S_LEN + st*64 + sc4;
  *(bf16x8*)&vt[voff]     = *(const bf16x8*)&ov[0];
  *(bf16x8*)&vt[voff + 8] = *(const bf16x8*)&ov[8];
}

// attention pass 1: ONLINE softmax stats, int8 QK^T (one MFMA per 16-row tile)
__global__ __launch_bounds__(256) void k_attn1(const i8* __restrict__ qh,
    const i8* __restrict__ kh, float* __restrict__ mrow, float* __restrict__ lrow,
    const float* __restrict__ sc, int* __restrict__ sci){
  __shared__ i8 Ks[64][64];
  __shared__ float red2[4];
  const int orig = blockIdx.x;
  const int tile = (orig & 7) * 128 + (orig >> 3);   // XCD-chunked swizzle
  const int bhead = tile >> 4, q0 = (tile & 15) * 64;
  const int tid = threadIdx.x, w = tid >> 6, lane = tid & 63;
  const int rr = lane & 15, g = lane >> 4;
  const float s_q = fmaxf((sc[7]*0.125f)/128.0f, EPSF);
  const float s_k = fmaxf(sc[8]/128.0f, EPSF);
  const float s_qk = s_q * s_k;
  const i8* qbase = qh + ((size_t)bhead*S_LEN + q0 + w*16)*DHEAD;
  const i8* kbase = kh + (size_t)bhead*S_LEN*DHEAD;
  i32x4 a = *(const i32x4*)&qbase[rr*DHEAD + g*16];
  // staging: row = w*16 + (lane>>2); 4 chunks of 16B per 64B row
  const int srow = w*16 + (lane >> 2);
  const int sco  = ((lane & 3) ^ ((srow >> 1) & 3)) << 4;
  float m[4] = {-1e30f, -1e30f, -1e30f, -1e30f};
  float l[4] = {0.f, 0.f, 0.f, 0.f};
  for (int cch = 0; cch < 16; cch++){
    const int n0 = cch * 64;
    __syncthreads();
    GLOAD16(&kbase[(size_t)(n0 + srow)*DHEAD + sco], &Ks[w*16][0]);
    __syncthreads();
    float sv[4][4];
#pragma unroll
    for (int nt = 0; nt < 4; nt++){
      int row = nt*16 + rr;
      i32x4 b = *(const i32x4*)((const i8*)Ks + row*64 + (((g ^ ((row >> 1) & 3))) << 4));
      i32x4 acc = {};
      acc = MFMAI8(a, b, acc);
#pragma unroll
      for (int r = 0; r < 4; r++) sv[nt][r] = (float)acc[r]*s_qk;
    }
#pragma unroll
    for (int r = 0; r < 4; r++){
      float cm = fmaxf(fmaxf(sv[0][r], sv[1][r]), fmaxf(sv[2][r], sv[3][r]));
      float mn = fmaxf(m[r], cm);
      l[r] *= EXP2F((m[r] - mn)*LOG2E);      // 1.0 when max unchanged
      m[r] = mn;
#pragma unroll
      for (int nt = 0; nt < 4; nt++)
        l[r] += EXP2F((sv[nt][r] - m[r])*LOG2E);
    }
  }
  // merge (m,l) across the 16 lanes of each column group
#pragma unroll
  for (int off = 1; off < 16; off <<= 1){
#pragma unroll
    for (int r = 0; r < 4; r++){
      float mo = __shfl_xor(m[r], off), lo = __shfl_xor(l[r], off);
      float mn = fmaxf(m[r], mo);
      l[r] = l[r]*EXP2F((m[r] - mn)*LOG2E) + lo*EXP2F((mo - mn)*LOG2E);
      m[r] = mn;
    }
  }
  if (rr == 0){
    int rowb = q0 + w*16 + g*4;
#pragma unroll
    for (int r = 0; r < 4; r++){
      mrow[(size_t)bhead*S_LEN + rowb + r] = m[r];
      lrow[(size_t)bhead*S_LEN + rowb + r] = l[r];
    }
  }
  // block max of 1/l -> sci[13] (for s_a)
  float im = 0.0f;
#pragma unroll
  for (int r = 0; r < 4; r++) im = fmaxf(im, 1.0f / l[r]);
  im = wave_max(im);
  if (lane == 0) red2[w] = im;
  __syncthreads();
  if (tid == 0){
    float mm = fmaxf(fmaxf(red2[0], red2[1]), fmaxf(red2[2], red2[3]));
    atomicMax(sci + 13, __float_as_int(mm));
  }
}

__global__ void k_sa_final(float* sc, const int* sci){
  if (threadIdx.x == 0)
    sc[11] = fmaxf(__int_as_float(sci[13]) / 255.0f, EPSF);
}

// attention pass 2: int8 QK^T recompute (bit-identical), quantize P, bf16 PV
__global__ __launch_bounds__(256) void k_attn2(const i8* __restrict__ qh,
    const i8* __restrict__ kh, const u16* __restrict__ vt,
    const float* __restrict__ mrow, const float* __restrict__ lrow,
    float* __restrict__ aout, const float* __restrict__ sc, int* __restrict__ amax_out){
  __shared__ i8 Ks[64][64];
  __shared__ u16 Vs[64][64];
  __shared__ u16 P[4][16][72];
  __shared__ float red[4];
  const int orig = blockIdx.x;
  const int tile = (orig & 7) * 128 + (orig >> 3);   // XCD-chunked swizzle
  const int bhead = tile >> 4, q0 = (tile & 15) * 64;
  const int tid = threadIdx.x, w = tid >> 6, lane = tid & 63;
  const int rr = lane & 15, g = lane >> 4, kk = g * 8;
  const int lr3 = lane >> 3, lc = lane & 7;
  const float s_q = fmaxf((sc[7]*0.125f)/128.0f, EPSF);
  const float s_k = fmaxf(sc[8]/128.0f, EPSF);
  const float s_qk = s_q * s_k;
  const float s_v = fmaxf(sc[9]/128.0f, EPSF);
  const float s_a = sc[11];
  const float fac = s_a * s_v;
  const i8* qbase = qh + ((size_t)bhead*S_LEN + q0 + w*16)*DHEAD;
  const i8* kbase = kh + (size_t)bhead*S_LEN*DHEAD;
  const u16* vbase = vt + (size_t)bhead*DHEAD*S_LEN;
  i32x4 a = *(const i32x4*)&qbase[rr*DHEAD + g*16];
  float mr[4], inv[4];
  {
    int rowb = q0 + w*16 + g*4;
#pragma unroll
    for (int r = 0; r < 4; r++){
      mr[r]  = mrow[(size_t)bhead*S_LEN + rowb + r];
      inv[r] = 1.0f / (lrow[(size_t)bhead*S_LEN + rowb + r] * s_a);
    }
  }
  const int srow = w*16 + (lane >> 2);
  const int sco  = ((lane & 3) ^ ((srow >> 1) & 3)) << 4;
  f32x4 cpv[4] = {};
  for (int cch = 0; cch < 16; cch++){
    const int n0 = cch * 64;
    __syncthreads();
    GLOAD16(&kbase[(size_t)(n0 + srow)*DHEAD + sco], &Ks[w*16][0]);
#pragma unroll
    for (int i = 0; i < 2; i++){
      int d = w*16 + i*8 + lr3;
      GLOAD16(&vbase[(size_t)d*S_LEN + n0 + ((lc ^ (d & 7)) << 3)], &Vs[w*16 + i*8][0]);
    }
    __syncthreads();
#pragma unroll
    for (int nt = 0; nt < 4; nt++){
      int row = nt*16 + rr;
      i32x4 b = *(const i32x4*)((const i8*)Ks + row*64 + (((g ^ ((row >> 1) & 3))) << 4));
      i32x4 acc = {};
      acc = MFMAI8(a, b, acc);
#pragma unroll
      for (int r = 0; r < 4; r++){
        float e  = EXP2F(((float)acc[r]*s_qk - mr[r])*LOG2E);
        float pq = fminf(rintf(e * inv[r]), 255.0f);
        P[w][g*4 + r][nt*16 + rr] = f2bf(pq);
      }
    }
    // PV: within-wave P dependency (compiler inserts lgkmcnt wait; no barrier needed)
    bf16x8 pa0 = *(const bf16x8*)&P[w][rr][kk];
    bf16x8 pa1 = *(const bf16x8*)&P[w][rr][32 + kk];
#pragma unroll
    for (int f = 0; f < 4; f++){
      int row = f*16 + rr;
      bf16x8 v0 = *(const bf16x8*)((const u16*)Vs + row*64 + (((g    ) ^ (row & 7)) << 3));
      bf16x8 v1 = *(const bf16x8*)((const u16*)Vs + row*64 + (((4 + g) ^ (row & 7)) << 3));
      cpv[f] = MFMA16(pa0, v0, cpv[f]);
      cpv[f] = MFMA16(pa1, v1, cpv[f]);
    }
  }
  const int b = bhead >> 4, hh = bhead & 15;
  float lmax = 0.0f;
#pragma unroll
  for (int f = 0; f < 4; f++){
    int d = f*16 + rr;
#pragma unroll
    for (int r = 0; r < 4; r++){
      int srow2 = q0 + w*16 + g*4 + r;
      float y = fac * cpv[f][r];
      aout[(size_t)(srow2*BATCH + b)*EMB + hh*DHEAD + d] = y;
      lmax = fmaxf(lmax, fabsf(y));
    }
  }
  lmax = wave_max(lmax);
  __syncthreads();
  if (lane == 0) red[w] = lmax;
  __syncthreads();
  if (tid == 0){
    float mm = fmaxf(fmaxf(red[0], red[1]), fmaxf(red[2], red[3]));
    atomicMax(amax_out, __float_as_int(mm));
  }
}

extern "C" void kernel_launch(void* const* d_in, const int* in_sizes, int n_in,
                              void* d_out, int out_size, void* d_ws, size_t ws_size,
                              hipStream_t stream){
  const float* query = (const float*)d_in[0];
  const float* key   = (const float*)d_in[1];
  const float* value = (const float*)d_in[2];
  const float* inW   = (const float*)d_in[3];
  const float* inB   = (const float*)d_in[4];
  const float* outW  = (const float*)d_in[5];
  const float* outB  = (const float*)d_in[6];
  float* out = (float*)d_out;

  char* ws = (char*)d_ws;
  float* sc  = (float*)ws;
  int*   sci = (int*)ws;
  u8* WQQ = (u8*)(ws + 256);                 // weights int8, 1MB each
  u8* WKQ = WQQ + 1024*1024;
  u8* WVQ = WKQ + 1024*1024;
  u8* WOQ = WVQ + 1024*1024;
  u8* XQ  = WOQ + 1024*1024;                 // acts int8, 4MB each
  u8* XK  = XQ + (size_t)NTOK*1024;
  u8* XV  = XK + (size_t)NTOK*1024;
  float* QF = (float*)(XV + (size_t)NTOK*1024); // f32, 16MB each
  float* KF = QF + (size_t)NTOK*1024;
  float* VF = KF + (size_t)NTOK*1024;
  u16* VT = (u16*)(VF + (size_t)NTOK*1024);  // bf16 V^T, 8MB
  float* MROW = (float*)(VT + (size_t)BHEAD*DHEAD*S_LEN);
  float* LROW = MROW + BHEAD*S_LEN;
  // reuse (lifetimes are disjoint along the serial stream):
  i8* QH  = (i8*)XQ;   i8* KH = (i8*)XK;     // proj-input quants dead after GEMMs
  float* AOUT = QF;                          // q f32 dead after k_quant_heads
  u8* AOQ = XV;                              // v int8 input dead after gemm3

  AQTable tab;
  tab.d[0] = { query,             XQ,  NTOK*1024/4, 0, 128.f, -128.f };
  tab.d[1] = { key,               XK,  NTOK*1024/4, 1, 128.f, -128.f };
  tab.d[2] = { value,             XV,  NTOK*1024/4, 2, 128.f, -128.f };
  tab.d[3] = { inW,               WQQ, 1024*1024/4, 3, 127.f, -127.f };
  tab.d[4] = { inW + 1024*1024,   WKQ, 1024*1024/4, 4, 127.f, -127.f };
  tab.d[5] = { inW + 2*1024*1024, WVQ, 1024*1024/4, 5, 127.f, -127.f };
  tab.d[6] = { outW,              WOQ, 1024*1024/4, 6, 127.f, -127.f };

  k_zero<<<1, 64, 0, stream>>>(sc);
  k_absmax7<<<2048, 256, 0, stream>>>(tab, sci);
  k_quant7<<<2048, 256, 0, stream>>>(tab, sc);
  k_gemm3<<<768, 512, 0, stream>>>((const i8*)XQ, (const i8*)WQQ, inB, QF, sc, sci);
  k_quant_heads<<<1024, 256, 0, stream>>>(QF, KF, VF, QH, KH, VT, sc);
  k_attn1<<<1024, 256, 0, stream>>>(QH, KH, MROW, LROW, sc, sci);
  k_sa_final<<<1, 64, 0, stream>>>(sc, sci);
  k_attn2<<<1024, 256, 0, stream>>>(QH, KH, VT, MROW, LROW, AOUT, sc, sci + 10);
  k_quant<<<1024, 256, 0, stream>>>(AOUT, AOQ, NTOK*1024/4, sc, 10);
  k_gemm1<<<256, 512, 0, stream>>>((const i8*)AOQ, (const i8*)WOQ, outB, out, sc, 10, 6, sci + 12);
}